// Round 5
// baseline (375.963 us; speedup 1.0000x reference)
//
#include <hip/hip_runtime.h>
#include <hip/hip_bf16.h>

#define SEQ 2048
#define DMODEL 2048
#define NHEAD 8
#define DHEAD 256

typedef _Float16 v8h __attribute__((ext_vector_type(8)));
typedef unsigned short v8u __attribute__((ext_vector_type(8)));
typedef float v4f __attribute__((ext_vector_type(4)));

__device__ __forceinline__ float b2f(unsigned short s) {
    return __uint_as_float(((unsigned)s) << 16);
}
__device__ __forceinline__ unsigned short f2b(float f) {
    unsigned u = __float_as_uint(f);
    u += 0x7fffu + ((u >> 16) & 1u);   // RNE
    return (unsigned short)(u >> 16);
}
__device__ __forceinline__ unsigned short f2h(float f) {
    _Float16 h = (_Float16)f;
    return __builtin_bit_cast(unsigned short, h);
}
__device__ __forceinline__ float h2f(unsigned short s) {
    return (float)__builtin_bit_cast(_Float16, s);
}

// ---------------------------------------------------------------- detect dtype
__global__ __launch_bounds__(256) void k_detect(const unsigned short* q, int* flag) {
    __shared__ int cnt;
    if (threadIdx.x == 0) cnt = 0;
    __syncthreads();
    int wild = 0;
    for (int i = threadIdx.x; i < 2048; i += 256) {
        float x = b2f(q[i]);
        float ax = fabsf(x);
        if (!(ax <= 100.0f) || (x != 0.0f && ax < 1e-6f)) wild++;
    }
    atomicAdd(&cnt, wild);
    __syncthreads();
    if (threadIdx.x == 0) *flag = (cnt < 256) ? 1 : 0;  // 1 = bf16, 0 = f32
}

// ----------------------------------------------------------- out_weight -> f32
__global__ __launch_bounds__(256) void k_cvt_gw(const void* ow, const int* flag, float* gw) {
    int bf = *(volatile const int*)flag;
    int i = blockIdx.x * 256 + threadIdx.x;
    gw[i] = bf ? b2f(((const unsigned short*)ow)[i]) : ((const float*)ow)[i];
}

// ------------------------------------------------------------- fused pre-pass
// grid (32 s-chunks, 96 = 3 tensors x 32 d-chunks). One read of q/k/v:
//   q,k -> fp16 qb/kb (straight), v -> fp16 vT (transposed via LDS),
//   gate partials (f32) from the same LDS-resident tile via atomics.
__global__ __launch_bounds__(256) void k_prep(const void* q, const void* k, const void* v,
                                              const void* igk, const void* fgk,
                                              const int* flag,
                                              unsigned short* qb, unsigned short* kb,
                                              unsigned short* vT,
                                              float* ipre, float* fpre) {
    __shared__ float xf[64][68];
    __shared__ float wl[64][16];
    const int bf = *(volatile const int*)flag;
    const int t  = blockIdx.y >> 5;        // 0=q,1=k,2=v
    const int dc = blockIdx.y & 31;
    const int s0 = blockIdx.x * 64;
    const int d0 = dc * 64;
    const int tid = threadIdx.x;
    const void* src = (t == 0) ? q : (t == 1) ? k : v;

    // ---- load 64x64 tile (f32 values), fill LDS; q/k: also emit fp16
    {
        int r = tid >> 2, c0 = (tid & 3) * 16;
        size_t base = (size_t)(s0 + r) * DMODEL + d0 + c0;
        float x[16];
        if (bf) {
            const unsigned short* sp = (const unsigned short*)src;
            v8u a = *(const v8u*)(sp + base);
            v8u b = *(const v8u*)(sp + base + 8);
#pragma unroll
            for (int j = 0; j < 8; j++) { x[j] = b2f(a[j]); x[8 + j] = b2f(b[j]); }
        } else {
            const float* sp = (const float*)src;
            v4f a0 = *(const v4f*)(sp + base),     a1 = *(const v4f*)(sp + base + 4);
            v4f a2 = *(const v4f*)(sp + base + 8), a3 = *(const v4f*)(sp + base + 12);
#pragma unroll
            for (int j = 0; j < 4; j++) {
                x[j] = a0[j]; x[4 + j] = a1[j]; x[8 + j] = a2[j]; x[12 + j] = a3[j];
            }
        }
#pragma unroll
        for (int j = 0; j < 16; j++) xf[r][c0 + j] = x[j];
        if (t < 2) {
            v8u o0, o1;
#pragma unroll
            for (int j = 0; j < 8; j++) { o0[j] = f2h(x[j]); o1[j] = f2h(x[8 + j]); }
            unsigned short* dst = (t == 0 ? qb : kb) + base;
            *(v8u*)dst = o0;
            *(v8u*)(dst + 8) = o1;
        }
    }
    // ---- stage gate-weight slice: rows (t*2048+d0+j), 8 igate + 8 fgate cols
    {
        int j = tid >> 2, wq = tid & 3;
        int grow = t * DMODEL + d0 + j;
        int off = (wq & 1) * 4;
        int dstoff = (wq < 2 ? 0 : 8) + off;
        if (bf) {
            const unsigned short* wp = (const unsigned short*)(wq < 2 ? igk : fgk);
#pragma unroll
            for (int u = 0; u < 4; u++) wl[j][dstoff + u] = b2f(wp[grow * 8 + off + u]);
        } else {
            const float* wp = (const float*)(wq < 2 ? igk : fgk);
            v4f wv = *(const v4f*)(wp + grow * 8 + off);
#pragma unroll
            for (int u = 0; u < 4; u++) wl[j][dstoff + u] = wv[u];
        }
    }
    __syncthreads();
    // ---- gate partials: thread (row, q4) sums 16 cols for 8h x 2 gates
    {
        int row = tid >> 2, q4 = tid & 3;
        float acc[16];
#pragma unroll
        for (int u = 0; u < 16; u++) acc[u] = 0.f;
#pragma unroll 4
        for (int j = 0; j < 16; j++) {
            float x = xf[row][q4 * 16 + j];
            const float* wr = wl[q4 * 16 + j];
#pragma unroll
            for (int u = 0; u < 16; u++) acc[u] += x * wr[u];
        }
#pragma unroll
        for (int u = 0; u < 16; u++) acc[u] += __shfl_xor(acc[u], 1, 64);
#pragma unroll
        for (int u = 0; u < 16; u++) acc[u] += __shfl_xor(acc[u], 2, 64);
        if (q4 == 0) {
#pragma unroll
            for (int u = 0; u < 8; u++) {
                atomicAdd(&ipre[u * SEQ + s0 + row], acc[u]);
                atomicAdd(&fpre[u * SEQ + s0 + row], acc[8 + u]);
            }
        }
    }
    // ---- v: transposed fp16 store
    if (t == 2) {
        int dr = tid >> 2, sc0 = (tid & 3) * 16;
        v8u o0, o1;
#pragma unroll
        for (int j = 0; j < 8; j++) {
            o0[j] = f2h(xf[sc0 + j][dr]);
            o1[j] = f2h(xf[sc0 + 8 + j][dr]);
        }
        size_t ob = (size_t)(d0 + dr) * SEQ + s0 + sc0;   // (d0+dr) == h*DHEAD+dh
        *(v8u*)(vT + ob) = o0;
        *(v8u*)(vT + ob + 8) = o1;
    }
}

// ---------------- per-head scans: cum(log_sigmoid(f)), a = i - cum, prefix-max
__global__ __launch_bounds__(256) void k_scan(const float* ipre, const float* fpre,
                                              const void* ib_, const void* fb_,
                                              const int* flag,
                                              float* a_g, float* amax_g) {
    __shared__ float sarr[256];
    int bf = *(volatile const int*)flag;
    int h = blockIdx.x, tid = threadIdx.x;
    float ib = bf ? b2f(((const unsigned short*)ib_)[h]) : ((const float*)ib_)[h];
    float fb = bf ? b2f(((const unsigned short*)fb_)[h]) : ((const float*)fb_)[h];
    int s0 = tid * 8;
    float lf[8], ip[8];
#pragma unroll
    for (int j = 0; j < 8; j++) {
        float fp = fpre[h * SEQ + s0 + j] + fb;
        lf[j] = fminf(fp, 0.0f) - log1pf(__expf(-fabsf(fp)));
        ip[j] = ipre[h * SEQ + s0 + j] + ib;
    }
    float cs[8]; float t = 0.f;
#pragma unroll
    for (int j = 0; j < 8; j++) { t += lf[j]; cs[j] = t; }
    sarr[tid] = t; __syncthreads();
    for (int ofs = 1; ofs < 256; ofs <<= 1) {
        float val = sarr[tid];
        if (tid >= ofs) val += sarr[tid - ofs];
        __syncthreads(); sarr[tid] = val; __syncthreads();
    }
    float excl = (tid > 0) ? sarr[tid - 1] : 0.0f;
    float cum[8], av[8];
#pragma unroll
    for (int j = 0; j < 8; j++) { cum[j] = excl + cs[j]; av[j] = ip[j] - cum[j]; }
    float mx = av[0];
#pragma unroll
    for (int j = 1; j < 8; j++) mx = fmaxf(mx, av[j]);
    __syncthreads(); sarr[tid] = mx; __syncthreads();
    for (int ofs = 1; ofs < 256; ofs <<= 1) {
        float val = sarr[tid];
        if (tid >= ofs) val = fmaxf(val, sarr[tid - ofs]);
        __syncthreads(); sarr[tid] = val; __syncthreads();
    }
    float run = (tid > 0) ? sarr[tid - 1] : -3.0e38f;
#pragma unroll
    for (int j = 0; j < 8; j++) {
        run = fmaxf(run, av[j]);
        int s = s0 + j;
        a_g[h * SEQ + s]    = av[j];
        amax_g[h * SEQ + s] = run;
    }
}

// --------------------------------------------------------------- main kernel
// 2 waves per block; wave w handles s-tiles js ≡ w (mod 2). Zero barriers in
// the K-loop (private per-wave P scratch); single barrier + LDS add combines
// the two partial accumulators before the in-register LayerNorm epilogue.
// 1024 blocks x 128 thr = 4 blocks/CU = 2 waves/SIMD (VGPR-capped).
__global__ __launch_bounds__(128, 2) void k_main(const unsigned short* __restrict__ qb,
                                                 const unsigned short* __restrict__ kb,
                                                 const unsigned short* __restrict__ vT,
                                                 const float* __restrict__ a_g,
                                                 const float* __restrict__ amax_g,
                                                 const float* __restrict__ gw,
                                                 const int* flag, void* out) {
    __shared__ __align__(16) unsigned short P_hi[2][16][36];
    __shared__ __align__(16) unsigned short P_lo[2][16][36];
    __shared__ __align__(16) v4f cbuf[16 * 64];   // 16 KB combine buffer

    const int bid  = blockIdx.x;          // 0..1023
    const int T    = 127 - (bid >> 3);    // long strips dispatch first
    const int h    = bid & 7;
    const int t0   = T * 16;
    const int tid  = threadIdx.x;
    const int w    = tid >> 6;            // wave 0/1
    const int lane = tid & 63;
    const int l15  = lane & 15;
    const int qd   = lane >> 4;           // quad 0..3
    const int hd0  = h * DHEAD;
    const int hSEQ = h * SEQ;
    const int nS   = (T + 2) >> 1;        // number of 32-col s-tiles
    const int bf   = *(volatile const int*)flag;

    // persistent q A-frags (16 rows x 256 d)
    v8h qf[8];
    {
        const unsigned short* qp = qb + (size_t)(t0 + l15) * DMODEL + hd0 + qd * 8;
#pragma unroll
        for (int d = 0; d < 8; d++) qf[d] = *(const v8h*)(qp + d * 32);
    }
    float amax[4];
#pragma unroll
    for (int r = 0; r < 4; r++) amax[r] = amax_g[hSEQ + t0 + qd * 4 + r];

    const unsigned short* kp = kb + (size_t)l15 * DMODEL + hd0 + qd * 8;
    const unsigned short* vp = vT + (size_t)(hd0 + l15) * SEQ + qd * 8;

    const v4f vzero = {0.f, 0.f, 0.f, 0.f};
    v4f acc[16];
#pragma unroll
    for (int nn = 0; nn < 16; nn++) acc[nn] = vzero;

    v8h kfA[16], kfB[16];
    int js = w;
    if (js < nS) {
        const int s0 = js * 32;
#pragma unroll
        for (int nt = 0; nt < 2; nt++)
#pragma unroll
            for (int d = 0; d < 8; d++)
                kfA[nt * 8 + d] = *(const v8h*)(kp + (size_t)(s0 + nt * 16) * DMODEL + d * 32);
    }

#define STEP(KC, KN)                                                                     \
    do {                                                                                 \
        const int s0 = js * 32;                                                          \
        v8h vf[16];                                                                      \
        _Pragma("unroll") for (int nn = 0; nn < 16; nn++)                                \
            vf[nn] = *(const v8h*)(vp + (size_t)(nn * 16) * SEQ + s0);                   \
        float a0 = a_g[hSEQ + s0 + l15];                                                 \
        float a1 = a_g[hSEQ + s0 + 16 + l15];                                            \
        v4f c0 = vzero, c1 = vzero;                                                      \
        _Pragma("unroll") for (int d = 0; d < 8; d++) {                                  \
            c0 = __builtin_amdgcn_mfma_f32_16x16x32_f16(qf[d], KC[d], c0, 0, 0, 0);      \
            c1 = __builtin_amdgcn_mfma_f32_16x16x32_f16(qf[d], KC[8 + d], c1, 0, 0, 0);  \
        }                                                                                \
        if (js + 2 < nS) {                                                               \
            _Pragma("unroll") for (int nt = 0; nt < 2; nt++)                             \
            _Pragma("unroll") for (int d = 0; d < 8; d++)                                 \
                KN[nt * 8 + d] =                                                         \
                    *(const v8h*)(kp + (size_t)(s0 + 64 + nt * 16) * DMODEL + d * 32);   \
        }                                                                                \
        const bool last = (js == nS - 1);                                                \
        _Pragma("unroll") for (int r = 0; r < 4; r++) {                                  \
            int row = qd * 4 + r, trow = t0 + row;                                       \
            float v0 = c0[r] * 0.0625f * __expf(fminf(a0 - amax[r], 0.f));               \
            float v1 = c1[r] * 0.0625f * __expf(fminf(a1 - amax[r], 0.f));               \
            if (last && (s0 + l15 > trow)) v0 = 0.f;                                     \
            if (last && (s0 + 16 + l15 > trow)) v1 = 0.f;                                \
            unsigned short h0 = f2h(v0), h1 = f2h(v1);                                   \
            P_hi[w][row][l15] = h0;      P_hi[w][row][16 + l15] = h1;                    \
            P_lo[w][row][l15] = f2h(v0 - h2f(h0));                                       \
            P_lo[w][row][16 + l15] = f2h(v1 - h2f(h1));                                  \
        }                                                                                \
        v8h aH = *(const v8h*)&P_hi[w][l15][qd * 8];                                     \
        v8h aL = *(const v8h*)&P_lo[w][l15][qd * 8];                                     \
        _Pragma("unroll") for (int nn = 0; nn < 16; nn++) {                              \
            acc[nn] = __builtin_amdgcn_mfma_f32_16x16x32_f16(aH, vf[nn], acc[nn], 0, 0, 0); \
            acc[nn] = __builtin_amdgcn_mfma_f32_16x16x32_f16(aL, vf[nn], acc[nn], 0, 0, 0); \
        }                                                                                \
    } while (0)

    while (js < nS) {
        STEP(kfA, kfB);
        js += 2;
        if (js >= nS) break;
        STEP(kfB, kfA);
        js += 2;
    }
#undef STEP

    // ---- combine the two waves' partial sums, then LayerNorm epilogue
    __syncthreads();
    if (w == 1) {
#pragma unroll
        for (int nn = 0; nn < 16; nn++) cbuf[nn * 64 + lane] = acc[nn];
    }
    __syncthreads();
    if (w == 0) {
#pragma unroll
        for (int nn = 0; nn < 16; nn++) acc[nn] += cbuf[nn * 64 + lane];
        float gwv[16];
#pragma unroll
        for (int nn = 0; nn < 16; nn++) gwv[nn] = gw[hd0 + nn * 16 + l15];
#pragma unroll
        for (int r = 0; r < 4; r++) {
            float sm = 0.f, sq = 0.f;
#pragma unroll
            for (int nn = 0; nn < 16; nn++) { float x = acc[nn][r]; sm += x; sq += x * x; }
#pragma unroll
            for (int m = 1; m < 16; m <<= 1) {
                sm += __shfl_xor(sm, m, 64);
                sq += __shfl_xor(sq, m, 64);
            }
            float mean = sm * (1.0f / 256.0f);
            float var  = fmaxf(sq * (1.0f / 256.0f) - mean * mean, 0.0f);
            float rstd = rsqrtf(var + 1e-6f);
            size_t ob = (size_t)(t0 + qd * 4 + r) * DMODEL + hd0 + l15;
            if (bf) {
                unsigned short* o = (unsigned short*)out;
#pragma unroll
                for (int nn = 0; nn < 16; nn++)
                    o[ob + nn * 16] = f2b((acc[nn][r] - mean) * rstd * gwv[nn]);
            } else {
                float* o = (float*)out;
#pragma unroll
                for (int nn = 0; nn < 16; nn++)
                    o[ob + nn * 16] = (acc[nn][r] - mean) * rstd * gwv[nn];
            }
        }
    }
}

// ---------------------------------------------------------------------- host
extern "C" void kernel_launch(void* const* d_in, const int* in_sizes, int n_in,
                              void* d_out, int out_size, void* d_ws, size_t ws_size,
                              hipStream_t stream) {
    const void* q   = d_in[0];
    const void* k   = d_in[1];
    const void* v   = d_in[2];
    const void* igk = d_in[3];
    const void* igb = d_in[4];
    const void* fgk = d_in[5];
    const void* fgb = d_in[6];
    const void* ow  = d_in[7];

    char* ws = (char*)d_ws;
    int*   flag   = (int*)(ws + 0);
    float* ipre   = (float*)(ws + 1024);
    float* fpre   = (float*)(ws + 1024 + 1 * 65536);
    float* a_g    = (float*)(ws + 1024 + 2 * 65536);
    float* amax_g = (float*)(ws + 1024 + 3 * 65536);
    float* gw     = (float*)(ws + 1024 + 4 * 65536);
    unsigned short* qb = (unsigned short*)(ws + 1024 + 4 * 65536 + 8192);
    unsigned short* kb = qb + (size_t)SEQ * DMODEL;
    unsigned short* vT = kb + (size_t)SEQ * DMODEL;

    hipMemsetAsync(ipre, 0, 2 * 65536, stream);
    k_detect<<<1, 256, 0, stream>>>((const unsigned short*)q, flag);
    k_cvt_gw<<<8, 256, 0, stream>>>(ow, flag, gw);
    k_prep<<<dim3(32, 96), 256, 0, stream>>>(q, k, v, igk, fgk, flag, qb, kb, vT, ipre, fpre);
    k_scan<<<8, 256, 0, stream>>>(ipre, fpre, igb, fgb, flag, a_g, amax_g);
    k_main<<<1024, 128, 0, stream>>>(qb, kb, vT, a_g, amax_g, gw, flag, d_out);
}